// Round 1
// baseline (378.384 us; speedup 1.0000x reference)
//
#include <hip/hip_runtime.h>
#include <stdint.h>

// Binarized ConvNet via XOR+popcount on packed bits.
// BN stats = exact integer sums (sharded global atomics); BN+sign folded into
// exact per-channel integer thresholds, computed ONCE by the last-arriving
// block of the producing kernel (atomic-counter pattern) instead of
// redundantly per consumer wave.  kB writes output directly from registers
// (no LDS staging) -> LDS 22KB -> 4.4KB -> 8 blocks/CU.

#define NB 8192
typedef unsigned long long ull;

// ---- ws layout ----
#define OFF_C1  ((size_t)0)                    // int8 [NB][196pos][32ch]
#define SZ_C1   ((size_t)NB*6272)
#define OFF_C2  (OFF_C1 + SZ_C1)               // int8 [NB][64ch][64pos] (o/2)
#define SZ_C2   ((size_t)NB*4096)
#define OFF_FC  (OFF_C2 + SZ_C2)               // int32 [NB][10]
#define SZ_FC   ((size_t)NB*10*4)
#define OFF_S1  (OFF_FC + SZ_FC)               // int  [8][32][2]   2048 B
#define OFF_S2  (OFF_S1 + 2048)                // ull  [8][64][2]   8192 B
#define OFF_S3  (OFF_S2 + 8192)                // ull  [8][10][2]   1280 used
#define OFF_CNT (OFF_S3 + 1280)                // 3 int counters (in zeroed pad)
#define OFF_T1  (OFF_S3 + 1344)                // int T1[32] + flipn1 (33 ints)
#define OFF_T2  (OFF_S3 + 1504)                // int T2[64] + ull flipn2
#define OFF_AB3 (OFF_S3 + 1792)                // float a3[10] b3[10]
#define OFF_W2B (OFF_S3 + 2048)                // ull w2bT[8][64] (word-idx major)
#define OFF_W3B (OFF_W2B + 4096)               // ull w3b[10][64ch], bit=pos

// exact integer threshold: bit = (v >= T) ^ flip  <=>  s*v + t > 0
__device__ inline void mk_thresh(double s, double t, int &T, int &flip) {
    if (s > 0.0) {
        int v = (int)floor(-t / s) - 2;
        for (int c = 0; c < 6; ++c) { if (s * (double)v + t > 0.0) break; ++v; }
        T = v; flip = 0;
    } else if (s < 0.0) {
        int v = (int)floor(-t / s) - 2;
        for (int c = 0; c < 6; ++c) { if (!(s * (double)v + t > 0.0)) break; ++v; }
        T = v; flip = 1;
    } else { T = -200; flip = (t > 0.0) ? 0 : 1; }
}
__device__ inline int clampT(int T, int lim) {
    return (T < -lim) ? -lim : (T > lim) ? lim : T;
}

// ------------------------------------------------------------------
// KA: conv1 (binary) + integer BN1 stats.  1 wave = 1 image, 4/block.
// Blocks >= 2048: weight packer, one THREAD per packed word (parallel).
// Last compute block also folds BN1 -> integer thresholds into ws.
// ------------------------------------------------------------------
__global__ __launch_bounds__(256) void kA_conv1(
    const float* __restrict__ x, const float* __restrict__ w1,
    const float* __restrict__ w2, const float* __restrict__ w3,
    const float* __restrict__ gm1, const float* __restrict__ bt1,
    int8_t* __restrict__ c1out, int* __restrict__ stats1,
    ull* __restrict__ w2bT, ull* __restrict__ w3b,
    int* __restrict__ T1g, int* __restrict__ cntA)
{
    const int tid = threadIdx.x, lane = tid & 63, wv = tid >> 6;

    if (blockIdx.x >= 2048) {   // ---- parallel weight packer blocks ----
        const int t = (blockIdx.x - 2048)*256 + tid;
        if (t < 512) {
            const int idx = t >> 6, k = t & 63;
            const int u = idx >> 1, pr = idx & 1;
            uint32_t lo = 0u, hi = 0u;
            #pragma unroll 8
            for (int c = 0; c < 32; ++c) {
                const float* wp = w2 + (((k*32 + c)*4 + u)*4 + 2*pr);
                lo |= (wp[0] > 0.f ? 1u : 0u) << c;
                hi |= (wp[1] > 0.f ? 1u : 0u) << c;
            }
            w2bT[t] = (ull)lo | ((ull)hi << 32);
        } else if (t < 1152) {
            const int w = t - 512;                 // w = m*64 + ch
            const float* wp = w3 + (size_t)(w >> 6)*4096 + (size_t)(w & 63)*64;
            ull bits = 0ull;
            #pragma unroll 16
            for (int k = 0; k < 64; ++k)
                bits |= (ull)(wp[k] > 0.f ? 1 : 0) << k;
            w3b[w] = bits;
        }
        return;
    }

    __shared__ ull sxb[4][16];              // 784 input sign bits, per wave
    __shared__ uint32_t wfilt[32];          // 25-bit filters
    __shared__ uint32_t outb[4][1568];      // int8 [196][32] as dwords, per wave
    __shared__ int lsum[32], lsq[32];
    __shared__ int lastA;

    if (tid < 32) {
        uint32_t f = 0u;
        #pragma unroll
        for (int q = 0; q < 25; ++q) f |= (w1[tid*25 + q] > 0.f ? 1u : 0u) << q;
        wfilt[tid] = f;
        lsum[tid] = 0; lsq[tid] = 0;
    }
    __syncthreads();          // barrier 1: wfilt + zeroed lsum visible
    const int n = blockIdx.x*4 + wv;
    // phase A: pack 784 input sign bits (13 ballot rounds) — wave-local
    #pragma unroll
    for (int t = 0; t < 13; ++t) {
        const int idx = t*64 + lane;
        const float v = (idx < 784) ? x[(size_t)n*784 + idx] : -1.f;
        const ull bal = __ballot(v > 0.f);
        if (lane == t) sxb[wv][t] = bal;
    }
    if (lane == 13) sxb[wv][13] = 0ull;
    // phase B: each lane computes up to 4 positions, 32 channels each
    for (int t = 0; t < 4; ++t) {
        const int p = t*64 + lane;
        if (p < 196) {
            const int i = p / 14, j = p - i*14;
            const uint32_t cmask = (j == 0) ? 0x1Cu : (j == 13) ? 0x0Fu : 0x1Fu;
            uint32_t win = 0u, vm = 0u;
            #pragma unroll
            for (int u = 0; u < 5; ++u) {
                const int r = 2*i + u - 2;
                if (r >= 0 && r < 28) {
                    const int bp = 28*r, w0 = bp >> 6, sh = bp & 63;
                    const ull a = sxb[wv][w0], b = sxb[wv][w0+1];
                    uint32_t row = (uint32_t)((a >> sh) | ((b << 1) << (63 - sh)));
                    row = (row & 0x0FFFFFFFu) << 2;
                    win |= ((row >> (2*j)) & 31u) << (5*u);
                    vm  |= cmask << (5*u);
                }
            }
            const int nv = __popc(vm);
            uint32_t dw[8];
            #pragma unroll
            for (int d = 0; d < 8; ++d) dw[d] = 0u;
            #pragma unroll
            for (int c = 0; c < 32; ++c) {
                const int diff = __popc((win ^ wfilt[c]) & vm);
                const int o = nv - 2*diff;
                dw[c >> 2] |= (uint32_t)(o & 255) << (8*(c & 3));
            }
            #pragma unroll
            for (int d = 0; d < 8; ++d) outb[wv][p*8 + d] = dw[d];
        }
    }
    {   // coalesced write [n][pos][ch] — wave-local, from LDS staging
        int4* dst = (int4*)(c1out + (size_t)n*6272);
        const int4* src = (const int4*)&outb[wv][0];
        #pragma unroll
        for (int t = 0; t < 7; ++t) {
            const int idx = t*64 + lane;
            if (idx < 392) dst[idx] = src[idx];
        }
    }
    {   // stats: dword reads, lane owns channel-dword d = lane&7
        int s4[4] = {0,0,0,0}, q4[4] = {0,0,0,0};
        const uint32_t* ob32 = &outb[wv][0];
        #pragma unroll
        for (int t = 0; t < 25; ++t) {
            const int idx = t*64 + lane;
            if (idx < 1568) {
                const uint32_t dwv = ob32[idx];
                #pragma unroll
                for (int qq = 0; qq < 4; ++qq) {
                    const int v = (int)((int8_t)(dwv >> (8*qq)));
                    s4[qq] += v; q4[qq] += v*v;
                }
            }
        }
        #pragma unroll
        for (int off = 8; off <= 32; off <<= 1) {
            #pragma unroll
            for (int qq = 0; qq < 4; ++qq) {
                s4[qq] += __shfl_xor(s4[qq], off);
                q4[qq] += __shfl_xor(q4[qq], off);
            }
        }
        if (lane < 8) {
            #pragma unroll
            for (int qq = 0; qq < 4; ++qq) {
                atomicAdd(&lsum[lane*4 + qq], s4[qq]);
                atomicAdd(&lsq[lane*4 + qq], q4[qq]);
            }
        }
    }
    __syncthreads();          // barrier 2: all waves' stats in lsum/lsq
    if (tid < 32) {
        const int shard = blockIdx.x & 7;
        atomicAdd(&stats1[(shard*32 + tid)*2 + 0], lsum[tid]);
        atomicAdd(&stats1[(shard*32 + tid)*2 + 1], lsq[tid]);
    }
    // ---- last-block: fold BN1 into integer thresholds (once, not per wave)
    __syncthreads();          // drains the stats atomics (vmcnt(0) at barrier)
    if (tid == 0) {
        __threadfence();
        lastA = (atomicAdd(cntA, 1) == 2047) ? 1 : 0;
    }
    __syncthreads();
    if (lastA && tid < 32) {
        long long s = 0, q = 0;
        for (int sh = 0; sh < 8; ++sh) {
            s += atomicAdd(&stats1[(sh*32 + tid)*2 + 0], 0);   // coherent read
            q += atomicAdd(&stats1[(sh*32 + tid)*2 + 1], 0);
        }
        const double N = 8192.0 * 196.0;
        const double mean = (double)s / N;
        const double var  = (double)q / N - mean*mean;
        const double a = (double)gm1[tid] / sqrt(var + 1e-5);
        const double b = (double)bt1[tid] - mean*a;
        int T, fl; mk_thresh(a, b, T, fl);
        T1g[tid] = clampT(T, 26);
        const uint32_t fn1 = ~(uint32_t)__ballot(fl != 0);
        if (tid == 0) T1g[32] = (int)fn1;
    }
}

// ------------------------------------------------------------------
// KB: load precomputed BN1 thresholds, binarize c1, conv2 xor+popc with
// b128 REGISTER sliding window (each row read once, broadcast), DIRECT
// register->global writeout (no LDS staging; 4x dwordx4 per lane).
// Last block folds BN2 -> thresholds.  1 wave = 1 image.
// ------------------------------------------------------------------
__global__ __launch_bounds__(256) void kB_conv2(
    const int8_t* __restrict__ c1out, const int* __restrict__ T1g,
    const ull* __restrict__ w2bT, const float* __restrict__ gm2,
    const float* __restrict__ bt2,
    int8_t* __restrict__ c2out, ull* __restrict__ stats2,
    int* __restrict__ T2g, int* __restrict__ cntB)
{
    __shared__ uint32_t BwU[4][14][16]; // packed input bits, 14 used/row, pad 16
    __shared__ int sT1[32];             // precomputed thresholds (block-shared)
    __shared__ int ssum[64], ssq[64];
    __shared__ int lastB;
    const int tid = threadIdx.x, lane = tid & 63, wv = tid >> 6;
    const int n = blockIdx.x*4 + wv;

    // W fragments from global (coalesced, L2-hot), split lo/hi dwords
    uint32_t Wlo[8], Whi[8];
    #pragma unroll
    for (int idx = 0; idx < 8; ++idx) {
        const uint2 w = ((const uint2*)w2bT)[idx*64 + lane];
        Wlo[idx] = w.x; Whi[idx] = w.y;
    }

    if (tid < 64) { ssum[tid] = 0; ssq[tid] = 0; }
    if (tid < 32) sT1[tid] = T1g[tid];
    const uint32_t flipn1 = (uint32_t)T1g[32];
    __syncthreads();          // barrier 1: sT1 + ssum zeros visible

    // pack phase — wave-local: binarize own image's 196 positions
    for (int t = lane; t < 196; t += 64) {
        const int r = t / 14, c = t - r*14;
        const uint4* src = (const uint4*)(c1out + ((size_t)n*196 + t)*32);
        const uint4 lo4 = src[0], hi4 = src[1];
        const uint32_t wsrc[8] = {lo4.x, lo4.y, lo4.z, lo4.w, hi4.x, hi4.y, hi4.z, hi4.w};
        uint32_t neg = 0u;
        #pragma unroll
        for (int d = 0; d < 8; ++d) {
            #pragma unroll
            for (int qq = 0; qq < 4; ++qq) {
                const int ch = d*4 + qq;
                const int v = (int)((int8_t)(wsrc[d] >> (8*qq)));
                neg |= ((uint32_t)(v - sT1[ch]) >> 31) << ch;   // 1 iff v<T
            }
        }
        BwU[wv][r][c] = neg ^ flipn1;
    }

    // compute phase: lane = out-channel; b128 register sliding window.
    // pair k = rows (2k, 2k+1); output row i uses pair i-1 (u=0,1) and pair i
    // (u=2,3).  Rows read ONCE via 4x ds_read_b128 each (wave-uniform bcast).
    uint32_t PA[32], PB[32];
#define LOADP(BUF, K)                                                          \
    {                                                                          \
        const uint4* r0 = (const uint4*)&BwU[wv][2*(K)][0];                    \
        const uint4* r1 = (const uint4*)&BwU[wv][2*(K)+1][0];                  \
        _Pragma("unroll")                                                      \
        for (int tt = 0; tt < 4; ++tt) {                                       \
            const uint4 v0 = r0[tt];                                           \
            BUF[4*tt+0] = v0.x; BUF[4*tt+1] = v0.y;                            \
            BUF[4*tt+2] = v0.z; BUF[4*tt+3] = v0.w;                            \
            const uint4 v1 = r1[tt];                                           \
            BUF[16+4*tt+0] = v1.x; BUF[16+4*tt+1] = v1.y;                      \
            BUF[16+4*tt+2] = v1.z; BUF[16+4*tt+3] = v1.w;                      \
        }                                                                      \
    }
#define UT(BUF, RO, UU)                                                        \
    {                                                                          \
        if (j >= 1) { D += __popc(BUF[(RO)*16 + 2*j-2] ^ Wlo[2*(UU)])          \
                         + __popc(BUF[(RO)*16 + 2*j-1] ^ Whi[2*(UU)]);   ++nw; } \
        if (j <= 6) { D += __popc(BUF[(RO)*16 + 2*j]   ^ Wlo[2*(UU)+1])        \
                         + __popc(BUF[(RO)*16 + 2*j+1] ^ Whi[2*(UU)+1]); ++nw; } \
    }
    int s = 0, q = 0;
    uint32_t* dst32 = (uint32_t*)(c2out + (size_t)n*4096 + (size_t)lane*64);
    uint32_t p0 = 0u, p1 = 0u;
    LOADP(PA, 0)
    #pragma unroll
    for (int i = 0; i < 8; ++i) {
        if (i >= 1 && i <= 6) {      // prefetch pair i into alternating buffer
            if (i & 1) { LOADP(PB, i) } else { LOADP(PA, i) }
        }
        uint32_t o0 = 0u, o1 = 0u;
        #pragma unroll
        for (int j = 0; j < 8; ++j) {
            int D = 0, nw = 0;
            if (i >= 1) {            // pair i-1: rows 2i-2 (u=0), 2i-1 (u=1)
                if ((i-1) & 1) { UT(PB, 0, 0) UT(PB, 1, 1) }
                else           { UT(PA, 0, 0) UT(PA, 1, 1) }
            }
            if (i <= 6) {            // pair i:   rows 2i (u=2), 2i+1 (u=3)
                if (i & 1) { UT(PB, 0, 2) UT(PB, 1, 3) }
                else       { UT(PA, 0, 2) UT(PA, 1, 3) }
            }
            const int o = 32*nw - D;         // = full/2, exact
            s += o; q += o*o;
            if (j < 4) o0 |= (uint32_t)(o & 255) << (8*j);
            else       o1 |= (uint32_t)(o & 255) << (8*(j-4));
        }
        // direct writeout: lane's 64B row is contiguous at [n][lane][.]
        if ((i & 1) == 0) { p0 = o0; p1 = o1; }
        else *(uint4*)(dst32 + 4*(i >> 1)) = make_uint4(p0, p1, o0, o1);
    }
#undef LOADP
#undef UT
    atomicAdd(&ssum[lane], s);
    atomicAdd(&ssq[lane], q);
    __syncthreads();          // barrier 2: all waves' stats in ssum/ssq
    if (tid < 64) {
        const int shard = blockIdx.x & 7;
        atomicAdd(&stats2[(shard*64 + tid)*2 + 0], (ull)(long long)ssum[tid]);
        atomicAdd(&stats2[(shard*64 + tid)*2 + 1], (ull)(long long)ssq[tid]);
    }
    // ---- last-block: fold BN2 into integer thresholds
    __syncthreads();
    if (tid == 0) {
        __threadfence();
        lastB = (atomicAdd(cntB, 1) == 2047) ? 1 : 0;
    }
    __syncthreads();
    if (lastB && tid < 64) {
        long long ss = 0, qq = 0;
        for (int sh = 0; sh < 8; ++sh) {
            ss += (long long)atomicAdd(&stats2[(sh*64 + tid)*2 + 0], 0ull);
            qq += (long long)atomicAdd(&stats2[(sh*64 + tid)*2 + 1], 0ull);
        }
        const double N = 8192.0 * 64.0;
        const double mh = (double)ss / N;
        const double vh = (double)qq / N - mh*mh;
        const double a = (double)gm2[tid] / sqrt(4.0*vh + 1e-5);
        const double b = (double)bt2[tid] - 2.0*mh*a;
        int T, fl; mk_thresh(2.0*a, b, T, fl);
        T2g[tid] = clampT(T, 200);
        const ull fn2 = ~__ballot(fl != 0);
        if (tid == 0) *(ull*)(T2g + 64) = fn2;
    }
}

// ------------------------------------------------------------------
// KC: load precomputed BN2 thresholds, binarize arithmetically, fc
// xor+popc, packed shuffle reduction, BN3 stats.  Last block folds
// BN3 -> float scale/bias for kD.  1 wave = 1 image.
// ------------------------------------------------------------------
__global__ __launch_bounds__(256) void kC_fc(
    const int8_t* __restrict__ c2o, const int* __restrict__ T2g,
    const ull* __restrict__ w3b, const float* __restrict__ gm3,
    const float* __restrict__ bt3,
    int* __restrict__ fc, ull* __restrict__ stats3,
    float* __restrict__ ab3, int* __restrict__ cntC)
{
    __shared__ int fco[4][10];
    __shared__ int s3[10], q3[10];
    __shared__ int lastC;
    const int tid = threadIdx.x, lane = tid & 63, wv = tid >> 6;
    if (tid < 10) { s3[tid] = 0; q3[tid] = 0; }
    const int T2 = T2g[lane];
    const ull flipn2 = *(const ull*)(T2g + 64);
    const int n = blockIdx.x*4 + wv;
    // load own channel's 64 bytes, build bit-word arithmetically
    const uint4* src = (const uint4*)(c2o + (size_t)n*4096 + lane*64);
    uint32_t neglo = 0u, neghi = 0u;
    #pragma unroll
    for (int r4 = 0; r4 < 4; ++r4) {
        const uint4 v4 = src[r4];
        const uint32_t wsrc[4] = {v4.x, v4.y, v4.z, v4.w};
        #pragma unroll
        for (int cc = 0; cc < 4; ++cc) {
            #pragma unroll
            for (int b = 0; b < 4; ++b) {
                const int p = r4*16 + cc*4 + b;
                const int v = (int)((int8_t)(wsrc[cc] >> (8*b)));
                const uint32_t bit = (uint32_t)(v - T2) >> 31;   // 1 iff v<T
                if (p < 32) neglo |= bit << p; else neghi |= bit << (p - 32);
            }
        }
    }
    const ull myw = ((ull)neglo | ((ull)neghi << 32)) ^ flipn2;
    // 10 outputs: popc of mismatch vs w3 words (global, L2-hot), packed reduce
    uint32_t pk[5];
    #pragma unroll
    for (int t = 0; t < 5; ++t) {
        const uint32_t pa = (uint32_t)__popcll(myw ^ w3b[(2*t+0)*64 + lane]);
        const uint32_t pb = (uint32_t)__popcll(myw ^ w3b[(2*t+1)*64 + lane]);
        pk[t] = pa | (pb << 16);
    }
    #pragma unroll
    for (int off = 32; off >= 1; off >>= 1) {
        #pragma unroll
        for (int t = 0; t < 5; ++t) pk[t] += __shfl_xor(pk[t], off);
    }
    if (lane == 0) {
        #pragma unroll
        for (int m = 0; m < 10; ++m) {
            const int tot = (pk[m >> 1] >> (16*(m & 1))) & 0xFFFF;
            fco[wv][m] = 4096 - 2*tot;
        }
    }
    __syncthreads();
    if (tid < 40) {
        const int li = tid / 10, m = tid - li*10;
        const int o = fco[li][m];
        fc[(size_t)(blockIdx.x*4 + li)*10 + m] = o;
        atomicAdd(&s3[m], o);
        atomicAdd(&q3[m], o*o);
    }
    __syncthreads();
    if (tid < 10) {
        const int shard = blockIdx.x & 7;
        atomicAdd(&stats3[(shard*10 + tid)*2 + 0], (ull)(long long)s3[tid]);
        atomicAdd(&stats3[(shard*10 + tid)*2 + 1], (ull)(long long)q3[tid]);
    }
    // ---- last-block: fold BN3 into float scale/bias for kD
    __syncthreads();
    if (tid == 0) {
        __threadfence();
        lastC = (atomicAdd(cntC, 1) == 2047) ? 1 : 0;
    }
    __syncthreads();
    if (lastC && tid < 10) {
        long long s = 0, q = 0;
        for (int sh = 0; sh < 8; ++sh) {
            s += (long long)atomicAdd(&stats3[(sh*10 + tid)*2 + 0], 0ull);
            q += (long long)atomicAdd(&stats3[(sh*10 + tid)*2 + 1], 0ull);
        }
        const double N = 8192.0;
        const double mean = (double)s / N;
        const double var  = (double)q / N - mean*mean;
        const double a = (double)gm3[tid] / sqrt(var + 1e-5);
        ab3[tid] = (float)a;
        ab3[10 + tid] = (float)((double)bt3[tid] - mean*a);
    }
}

// ------------------------------------------------------------------
// KD: apply precomputed BN3 scale/bias -> d_out (fp32)
// ------------------------------------------------------------------
__global__ __launch_bounds__(256) void kD_apply(
    const int* __restrict__ fc, const float* __restrict__ ab3,
    float* __restrict__ out)
{
    __shared__ float a3[10], b3[10];
    const int tid = threadIdx.x;
    if (tid < 10) { a3[tid] = ab3[tid]; b3[tid] = ab3[10 + tid]; }
    __syncthreads();
    const int e = blockIdx.x*256 + tid;
    if (e < NB*10) {
        const int m = e % 10;
        out[e] = fmaf(a3[m], (float)fc[e], b3[m]);
    }
}

extern "C" void kernel_launch(void* const* d_in, const int* in_sizes, int n_in,
                              void* d_out, int out_size, void* d_ws, size_t ws_size,
                              hipStream_t stream)
{
    const float* x   = (const float*)d_in[0];
    const float* w1  = (const float*)d_in[1];
    const float* gm1 = (const float*)d_in[2];
    const float* bt1 = (const float*)d_in[3];
    const float* w2  = (const float*)d_in[4];
    const float* gm2 = (const float*)d_in[5];
    const float* bt2 = (const float*)d_in[6];
    const float* w3  = (const float*)d_in[7];
    const float* gm3 = (const float*)d_in[8];
    const float* bt3 = (const float*)d_in[9];
    char* ws = (char*)d_ws;
    int8_t* c1o = (int8_t*)(ws + OFF_C1);
    int8_t* c2o = (int8_t*)(ws + OFF_C2);
    int*    fcb = (int*)(ws + OFF_FC);
    int*    s1  = (int*)(ws + OFF_S1);
    ull*    s2  = (ull*)(ws + OFF_S2);
    ull*    s3  = (ull*)(ws + OFF_S3);
    int*    cnt = (int*)(ws + OFF_CNT);
    int*    T1g = (int*)(ws + OFF_T1);
    int*    T2g = (int*)(ws + OFF_T2);
    float*  ab3 = (float*)(ws + OFF_AB3);
    ull*    w2bp = (ull*)(ws + OFF_W2B);
    ull*    w3bp = (ull*)(ws + OFF_W3B);

    // zeroes S1 + S2 + S3 (incl. counters/thresh scratch in S3 pad)
    (void)hipMemsetAsync(ws + OFF_S1, 0, 12288, stream);
    kA_conv1<<<2053, 256, 0, stream>>>(x, w1, w2, w3, gm1, bt1, c1o, s1,
                                       w2bp, w3bp, T1g, cnt + 0);
    kB_conv2<<<2048, 256, 0, stream>>>(c1o, T1g, w2bp, gm2, bt2, c2o, s2,
                                       T2g, cnt + 1);
    kC_fc   <<<2048, 256, 0, stream>>>(c2o, T2g, w3bp, gm3, bt3, fcb, s3,
                                       ab3, cnt + 2);
    kD_apply<<<320,  256, 0, stream>>>(fcb, ab3, (float*)d_out);
}

// Round 2
// 343.180 us; speedup vs baseline: 1.1026x; 1.1026x over previous
//
#include <hip/hip_runtime.h>
#include <stdint.h>

// Binarized ConvNet via XOR+popcount on packed bits.
// BN stats = exact integer sums (sharded global atomics); BN+sign folded into
// exact per-channel integer thresholds, computed ONCE by the last-arriving
// block of the producing kernel (atomic-counter pattern).  kB uses LDS-staged
// coalesced writeout (direct register->global stores proved catastrophic:
// WRITE_SIZE +60%, latency-bound collapse — round-1 post-mortem).

#define NB 8192
typedef unsigned long long ull;

// ---- ws layout ----
#define OFF_C1  ((size_t)0)                    // int8 [NB][196pos][32ch]
#define SZ_C1   ((size_t)NB*6272)
#define OFF_C2  (OFF_C1 + SZ_C1)               // int8 [NB][64ch][64pos] (o/2)
#define SZ_C2   (OFF_C2 + (size_t)NB*4096 - OFF_C2)
#define OFF_FC  (OFF_C2 + (size_t)NB*4096)     // int32 [NB][10]
#define OFF_S1  (OFF_FC + (size_t)NB*10*4)     // int  [8][32][2]   2048 B
#define OFF_S2  (OFF_S1 + 2048)                // ull  [8][64][2]   8192 B
#define OFF_S3  (OFF_S2 + 8192)                // ull  [8][10][2]   1280 used
#define OFF_CNT (OFF_S3 + 1280)                // 3 int counters (in zeroed pad)
#define OFF_T1  (OFF_S3 + 1344)                // int T1[32] + flipn1 (33 ints)
#define OFF_T2  (OFF_S3 + 1504)                // int T2[64] + ull flipn2
#define OFF_AB3 (OFF_S3 + 1792)                // float a3[10] b3[10]
#define OFF_W2B (OFF_S3 + 2048)                // ull w2bT[8][64] (word-idx major)
#define OFF_W3B (OFF_W2B + 4096)               // ull w3b[10][64ch], bit=pos

// exact integer threshold: bit = (v >= T) ^ flip  <=>  s*v + t > 0
__device__ inline void mk_thresh(double s, double t, int &T, int &flip) {
    if (s > 0.0) {
        int v = (int)floor(-t / s) - 2;
        for (int c = 0; c < 6; ++c) { if (s * (double)v + t > 0.0) break; ++v; }
        T = v; flip = 0;
    } else if (s < 0.0) {
        int v = (int)floor(-t / s) - 2;
        for (int c = 0; c < 6; ++c) { if (!(s * (double)v + t > 0.0)) break; ++v; }
        T = v; flip = 1;
    } else { T = -200; flip = (t > 0.0) ? 0 : 1; }
}
__device__ inline int clampT(int T, int lim) {
    return (T < -lim) ? -lim : (T > lim) ? lim : T;
}

// ------------------------------------------------------------------
// KA: conv1 (binary) + integer BN1 stats.  1 wave = 1 image, 4/block.
// Blocks >= 2048: weight packer, one THREAD per packed word (parallel).
// Last compute block also folds BN1 -> integer thresholds into ws.
// ------------------------------------------------------------------
__global__ __launch_bounds__(256) void kA_conv1(
    const float* __restrict__ x, const float* __restrict__ w1,
    const float* __restrict__ w2, const float* __restrict__ w3,
    const float* __restrict__ gm1, const float* __restrict__ bt1,
    int8_t* __restrict__ c1out, int* __restrict__ stats1,
    ull* __restrict__ w2bT, ull* __restrict__ w3b,
    int* __restrict__ T1g, int* __restrict__ cntA)
{
    const int tid = threadIdx.x, lane = tid & 63, wv = tid >> 6;

    if (blockIdx.x >= 2048) {   // ---- parallel weight packer blocks ----
        const int t = (blockIdx.x - 2048)*256 + tid;
        if (t < 512) {
            const int idx = t >> 6, k = t & 63;
            const int u = idx >> 1, pr = idx & 1;
            uint32_t lo = 0u, hi = 0u;
            #pragma unroll 8
            for (int c = 0; c < 32; ++c) {
                const float* wp = w2 + (((k*32 + c)*4 + u)*4 + 2*pr);
                lo |= (wp[0] > 0.f ? 1u : 0u) << c;
                hi |= (wp[1] > 0.f ? 1u : 0u) << c;
            }
            w2bT[t] = (ull)lo | ((ull)hi << 32);
        } else if (t < 1152) {
            const int w = t - 512;                 // w = m*64 + ch
            const float* wp = w3 + (size_t)(w >> 6)*4096 + (size_t)(w & 63)*64;
            ull bits = 0ull;
            #pragma unroll 16
            for (int k = 0; k < 64; ++k)
                bits |= (ull)(wp[k] > 0.f ? 1 : 0) << k;
            w3b[w] = bits;
        }
        return;
    }

    __shared__ ull sxb[4][16];              // 784 input sign bits, per wave
    __shared__ uint32_t wfilt[32];          // 25-bit filters
    __shared__ uint32_t outb[4][1568];      // int8 [196][32] as dwords, per wave
    __shared__ int lsum[32], lsq[32];
    __shared__ int lastA;

    if (tid < 32) {
        uint32_t f = 0u;
        #pragma unroll
        for (int q = 0; q < 25; ++q) f |= (w1[tid*25 + q] > 0.f ? 1u : 0u) << q;
        wfilt[tid] = f;
        lsum[tid] = 0; lsq[tid] = 0;
    }
    __syncthreads();          // barrier 1: wfilt + zeroed lsum visible
    const int n = blockIdx.x*4 + wv;
    // phase A: pack 784 input sign bits (13 ballot rounds) — wave-local
    #pragma unroll
    for (int t = 0; t < 13; ++t) {
        const int idx = t*64 + lane;
        const float v = (idx < 784) ? x[(size_t)n*784 + idx] : -1.f;
        const ull bal = __ballot(v > 0.f);
        if (lane == t) sxb[wv][t] = bal;
    }
    if (lane == 13) sxb[wv][13] = 0ull;
    // phase B: each lane computes up to 4 positions, 32 channels each
    for (int t = 0; t < 4; ++t) {
        const int p = t*64 + lane;
        if (p < 196) {
            const int i = p / 14, j = p - i*14;
            const uint32_t cmask = (j == 0) ? 0x1Cu : (j == 13) ? 0x0Fu : 0x1Fu;
            uint32_t win = 0u, vm = 0u;
            #pragma unroll
            for (int u = 0; u < 5; ++u) {
                const int r = 2*i + u - 2;
                if (r >= 0 && r < 28) {
                    const int bp = 28*r, w0 = bp >> 6, sh = bp & 63;
                    const ull a = sxb[wv][w0], b = sxb[wv][w0+1];
                    uint32_t row = (uint32_t)((a >> sh) | ((b << 1) << (63 - sh)));
                    row = (row & 0x0FFFFFFFu) << 2;
                    win |= ((row >> (2*j)) & 31u) << (5*u);
                    vm  |= cmask << (5*u);
                }
            }
            const int nv = __popc(vm);
            uint32_t dw[8];
            #pragma unroll
            for (int d = 0; d < 8; ++d) dw[d] = 0u;
            #pragma unroll
            for (int c = 0; c < 32; ++c) {
                const int diff = __popc((win ^ wfilt[c]) & vm);
                const int o = nv - 2*diff;
                dw[c >> 2] |= (uint32_t)(o & 255) << (8*(c & 3));
            }
            #pragma unroll
            for (int d = 0; d < 8; ++d) outb[wv][p*8 + d] = dw[d];
        }
    }
    {   // coalesced write [n][pos][ch] — wave-local, from LDS staging
        int4* dst = (int4*)(c1out + (size_t)n*6272);
        const int4* src = (const int4*)&outb[wv][0];
        #pragma unroll
        for (int t = 0; t < 7; ++t) {
            const int idx = t*64 + lane;
            if (idx < 392) dst[idx] = src[idx];
        }
    }
    {   // stats: dword reads, lane owns channel-dword d = lane&7
        int s4[4] = {0,0,0,0}, q4[4] = {0,0,0,0};
        const uint32_t* ob32 = &outb[wv][0];
        #pragma unroll
        for (int t = 0; t < 25; ++t) {
            const int idx = t*64 + lane;
            if (idx < 1568) {
                const uint32_t dwv = ob32[idx];
                #pragma unroll
                for (int qq = 0; qq < 4; ++qq) {
                    const int v = (int)((int8_t)(dwv >> (8*qq)));
                    s4[qq] += v; q4[qq] += v*v;
                }
            }
        }
        #pragma unroll
        for (int off = 8; off <= 32; off <<= 1) {
            #pragma unroll
            for (int qq = 0; qq < 4; ++qq) {
                s4[qq] += __shfl_xor(s4[qq], off);
                q4[qq] += __shfl_xor(q4[qq], off);
            }
        }
        if (lane < 8) {
            #pragma unroll
            for (int qq = 0; qq < 4; ++qq) {
                atomicAdd(&lsum[lane*4 + qq], s4[qq]);
                atomicAdd(&lsq[lane*4 + qq], q4[qq]);
            }
        }
    }
    __syncthreads();          // barrier 2: all waves' stats in lsum/lsq
    if (tid < 32) {
        const int shard = blockIdx.x & 7;
        atomicAdd(&stats1[(shard*32 + tid)*2 + 0], lsum[tid]);
        atomicAdd(&stats1[(shard*32 + tid)*2 + 1], lsq[tid]);
    }
    // ---- last-block: fold BN1 into integer thresholds (once, not per wave)
    __syncthreads();          // all waves' global stats atomics issued+done
    if (tid == 0) {
        __threadfence();
        lastA = (atomicAdd(cntA, 1) == 2047) ? 1 : 0;
    }
    __syncthreads();
    if (lastA && tid < 32) {
        long long s = 0, q = 0;
        for (int sh = 0; sh < 8; ++sh) {
            s += atomicAdd(&stats1[(sh*32 + tid)*2 + 0], 0);   // coherent read
            q += atomicAdd(&stats1[(sh*32 + tid)*2 + 1], 0);
        }
        const double N = 8192.0 * 196.0;
        const double mean = (double)s / N;
        const double var  = (double)q / N - mean*mean;
        const double a = (double)gm1[tid] / sqrt(var + 1e-5);
        const double b = (double)bt1[tid] - mean*a;
        int T, fl; mk_thresh(a, b, T, fl);
        T1g[tid] = clampT(T, 26);
        const uint32_t fn1 = ~(uint32_t)__ballot(fl != 0);
        if (tid == 0) T1g[32] = (int)fn1;
    }
}

// ------------------------------------------------------------------
// KB: load precomputed BN1 thresholds, binarize c1, conv2 xor+popc with
// b128 register sliding window (each row read once, broadcast), coalesced
// LDS-staged writeout, int8 o/2 out [n][ch][pos].  1 wave = 1 image.
// Last block folds BN2 -> thresholds.
// ------------------------------------------------------------------
__global__ __launch_bounds__(256) void kB_conv2(
    const int8_t* __restrict__ c1out, const int* __restrict__ T1g,
    const ull* __restrict__ w2bT, const float* __restrict__ gm2,
    const float* __restrict__ bt2,
    int8_t* __restrict__ c2out, ull* __restrict__ stats2,
    int* __restrict__ T2g, int* __restrict__ cntB)
{
    __shared__ uint32_t BwU[4][14][16]; // packed input bits, 14 used/row, pad 16
    __shared__ int sT1[32];             // precomputed thresholds (block-shared)
    __shared__ uint32_t cw[4][64][17];  // staged out dwords, pad 17 -> no conflict
    __shared__ int ssum[64], ssq[64];
    __shared__ int lastB;
    const int tid = threadIdx.x, lane = tid & 63, wv = tid >> 6;
    const int n = blockIdx.x*4 + wv;

    // W fragments from global (coalesced, L2-hot), split lo/hi dwords
    uint32_t Wlo[8], Whi[8];
    #pragma unroll
    for (int idx = 0; idx < 8; ++idx) {
        const uint2 w = ((const uint2*)w2bT)[idx*64 + lane];
        Wlo[idx] = w.x; Whi[idx] = w.y;
    }

    if (tid < 64) { ssum[tid] = 0; ssq[tid] = 0; }
    if (tid < 32) sT1[tid] = T1g[tid];
    const uint32_t flipn1 = (uint32_t)T1g[32];
    __syncthreads();          // barrier 1: sT1 + ssum zeros visible

    // pack phase — wave-local: binarize own image's 196 positions
    for (int t = lane; t < 196; t += 64) {
        const int r = t / 14, c = t - r*14;
        const uint4* src = (const uint4*)(c1out + ((size_t)n*196 + t)*32);
        const uint4 lo4 = src[0], hi4 = src[1];
        const uint32_t wsrc[8] = {lo4.x, lo4.y, lo4.z, lo4.w, hi4.x, hi4.y, hi4.z, hi4.w};
        uint32_t neg = 0u;
        #pragma unroll
        for (int d = 0; d < 8; ++d) {
            #pragma unroll
            for (int qq = 0; qq < 4; ++qq) {
                const int ch = d*4 + qq;
                const int v = (int)((int8_t)(wsrc[d] >> (8*qq)));
                neg |= ((uint32_t)(v - sT1[ch]) >> 31) << ch;   // 1 iff v<T
            }
        }
        BwU[wv][r][c] = neg ^ flipn1;
    }

    // compute phase: lane = out-channel; b128 register sliding window.
    // pair k = rows (2k, 2k+1); output row i uses pair i-1 (u=0,1) and pair i
    // (u=2,3).  Rows read ONCE via 4x ds_read_b128 each (wave-uniform bcast).
    uint32_t PA[32], PB[32];
#define LOADP(BUF, K)                                                          \
    {                                                                          \
        const uint4* r0 = (const uint4*)&BwU[wv][2*(K)][0];                    \
        const uint4* r1 = (const uint4*)&BwU[wv][2*(K)+1][0];                  \
        _Pragma("unroll")                                                      \
        for (int tt = 0; tt < 4; ++tt) {                                       \
            const uint4 v0 = r0[tt];                                           \
            BUF[4*tt+0] = v0.x; BUF[4*tt+1] = v0.y;                            \
            BUF[4*tt+2] = v0.z; BUF[4*tt+3] = v0.w;                            \
            const uint4 v1 = r1[tt];                                           \
            BUF[16+4*tt+0] = v1.x; BUF[16+4*tt+1] = v1.y;                      \
            BUF[16+4*tt+2] = v1.z; BUF[16+4*tt+3] = v1.w;                      \
        }                                                                      \
    }
#define UT(BUF, RO, UU)                                                        \
    {                                                                          \
        if (j >= 1) { D += __popc(BUF[(RO)*16 + 2*j-2] ^ Wlo[2*(UU)])          \
                         + __popc(BUF[(RO)*16 + 2*j-1] ^ Whi[2*(UU)]);   ++nw; } \
        if (j <= 6) { D += __popc(BUF[(RO)*16 + 2*j]   ^ Wlo[2*(UU)+1])        \
                         + __popc(BUF[(RO)*16 + 2*j+1] ^ Whi[2*(UU)+1]); ++nw; } \
    }
    int s = 0, q = 0;
    LOADP(PA, 0)
    #pragma unroll
    for (int i = 0; i < 8; ++i) {
        if (i >= 1 && i <= 6) {      // prefetch pair i into alternating buffer
            if (i & 1) { LOADP(PB, i) } else { LOADP(PA, i) }
        }
        uint32_t o0 = 0u, o1 = 0u;
        #pragma unroll
        for (int j = 0; j < 8; ++j) {
            int D = 0, nw = 0;
            if (i >= 1) {            // pair i-1: rows 2i-2 (u=0), 2i-1 (u=1)
                if ((i-1) & 1) { UT(PB, 0, 0) UT(PB, 1, 1) }
                else           { UT(PA, 0, 0) UT(PA, 1, 1) }
            }
            if (i <= 6) {            // pair i:   rows 2i (u=2), 2i+1 (u=3)
                if (i & 1) { UT(PB, 0, 2) UT(PB, 1, 3) }
                else       { UT(PA, 0, 2) UT(PA, 1, 3) }
            }
            const int o = 32*nw - D;         // = full/2, exact
            s += o; q += o*o;
            if (j < 4) o0 |= (uint32_t)(o & 255) << (8*j);
            else       o1 |= (uint32_t)(o & 255) << (8*(j-4));
        }
        cw[wv][lane][2*i]     = o0;
        cw[wv][lane][2*i + 1] = o1;
    }
#undef LOADP
#undef UT
    atomicAdd(&ssum[lane], s);
    atomicAdd(&ssq[lane], q);
    {   // coalesced writeout [n][ch][pos] — wave-local, dword-wise
        uint32_t* dst = (uint32_t*)(c2out + (size_t)n*4096);
        #pragma unroll
        for (int t = 0; t < 16; ++t) {
            const int g = t*64 + lane;
            dst[g] = cw[wv][g >> 4][g & 15];
        }
    }
    __syncthreads();          // barrier 2: all waves' stats in ssum/ssq
    if (tid < 64) {
        const int shard = blockIdx.x & 7;
        atomicAdd(&stats2[(shard*64 + tid)*2 + 0], (ull)(long long)ssum[tid]);
        atomicAdd(&stats2[(shard*64 + tid)*2 + 1], (ull)(long long)ssq[tid]);
    }
    // ---- last-block: fold BN2 into integer thresholds
    __syncthreads();
    if (tid == 0) {
        __threadfence();
        lastB = (atomicAdd(cntB, 1) == 2047) ? 1 : 0;
    }
    __syncthreads();
    if (lastB && tid < 64) {
        long long ss = 0, qq = 0;
        for (int sh = 0; sh < 8; ++sh) {
            ss += (long long)atomicAdd(&stats2[(sh*64 + tid)*2 + 0], 0ull);
            qq += (long long)atomicAdd(&stats2[(sh*64 + tid)*2 + 1], 0ull);
        }
        const double N = 8192.0 * 64.0;
        const double mh = (double)ss / N;
        const double vh = (double)qq / N - mh*mh;
        const double a = (double)gm2[tid] / sqrt(4.0*vh + 1e-5);
        const double b = (double)bt2[tid] - 2.0*mh*a;
        int T, fl; mk_thresh(2.0*a, b, T, fl);
        T2g[tid] = clampT(T, 200);
        const ull fn2 = ~__ballot(fl != 0);
        if (tid == 0) *(ull*)(T2g + 64) = fn2;
    }
}

// ------------------------------------------------------------------
// KC: load precomputed BN2 thresholds, binarize arithmetically, fc
// xor+popc, packed shuffle reduction, BN3 stats.  Last block folds
// BN3 -> float scale/bias for kD.  1 wave = 1 image.
// ------------------------------------------------------------------
__global__ __launch_bounds__(256) void kC_fc(
    const int8_t* __restrict__ c2o, const int* __restrict__ T2g,
    const ull* __restrict__ w3b, const float* __restrict__ gm3,
    const float* __restrict__ bt3,
    int* __restrict__ fc, ull* __restrict__ stats3,
    float* __restrict__ ab3, int* __restrict__ cntC)
{
    __shared__ int fco[4][10];
    __shared__ int s3[10], q3[10];
    __shared__ int lastC;
    const int tid = threadIdx.x, lane = tid & 63, wv = tid >> 6;
    if (tid < 10) { s3[tid] = 0; q3[tid] = 0; }
    const int T2 = T2g[lane];
    const ull flipn2 = *(const ull*)(T2g + 64);
    const int n = blockIdx.x*4 + wv;
    // load own channel's 64 bytes, build bit-word arithmetically
    const uint4* src = (const uint4*)(c2o + (size_t)n*4096 + lane*64);
    uint32_t neglo = 0u, neghi = 0u;
    #pragma unroll
    for (int r4 = 0; r4 < 4; ++r4) {
        const uint4 v4 = src[r4];
        const uint32_t wsrc[4] = {v4.x, v4.y, v4.z, v4.w};
        #pragma unroll
        for (int cc = 0; cc < 4; ++cc) {
            #pragma unroll
            for (int b = 0; b < 4; ++b) {
                const int p = r4*16 + cc*4 + b;
                const int v = (int)((int8_t)(wsrc[cc] >> (8*b)));
                const uint32_t bit = (uint32_t)(v - T2) >> 31;   // 1 iff v<T
                if (p < 32) neglo |= bit << p; else neghi |= bit << (p - 32);
            }
        }
    }
    const ull myw = ((ull)neglo | ((ull)neghi << 32)) ^ flipn2;
    // 10 outputs: popc of mismatch vs w3 words (global, L2-hot), packed reduce
    uint32_t pk[5];
    #pragma unroll
    for (int t = 0; t < 5; ++t) {
        const uint32_t pa = (uint32_t)__popcll(myw ^ w3b[(2*t+0)*64 + lane]);
        const uint32_t pb = (uint32_t)__popcll(myw ^ w3b[(2*t+1)*64 + lane]);
        pk[t] = pa | (pb << 16);
    }
    #pragma unroll
    for (int off = 32; off >= 1; off >>= 1) {
        #pragma unroll
        for (int t = 0; t < 5; ++t) pk[t] += __shfl_xor(pk[t], off);
    }
    if (lane == 0) {
        #pragma unroll
        for (int m = 0; m < 10; ++m) {
            const int tot = (pk[m >> 1] >> (16*(m & 1))) & 0xFFFF;
            fco[wv][m] = 4096 - 2*tot;
        }
    }
    __syncthreads();
    if (tid < 40) {
        const int li = tid / 10, m = tid - li*10;
        const int o = fco[li][m];
        fc[(size_t)(blockIdx.x*4 + li)*10 + m] = o;
        atomicAdd(&s3[m], o);
        atomicAdd(&q3[m], o*o);
    }
    __syncthreads();
    if (tid < 10) {
        const int shard = blockIdx.x & 7;
        atomicAdd(&stats3[(shard*10 + tid)*2 + 0], (ull)(long long)s3[tid]);
        atomicAdd(&stats3[(shard*10 + tid)*2 + 1], (ull)(long long)q3[tid]);
    }
    // ---- last-block: fold BN3 into float scale/bias for kD
    __syncthreads();
    if (tid == 0) {
        __threadfence();
        lastC = (atomicAdd(cntC, 1) == 2047) ? 1 : 0;
    }
    __syncthreads();
    if (lastC && tid < 10) {
        long long s = 0, q = 0;
        for (int sh = 0; sh < 8; ++sh) {
            s += (long long)atomicAdd(&stats3[(sh*10 + tid)*2 + 0], 0ull);
            q += (long long)atomicAdd(&stats3[(sh*10 + tid)*2 + 1], 0ull);
        }
        const double N = 8192.0;
        const double mean = (double)s / N;
        const double var  = (double)q / N - mean*mean;
        const double a = (double)gm3[tid] / sqrt(var + 1e-5);
        ab3[tid] = (float)a;
        ab3[10 + tid] = (float)((double)bt3[tid] - mean*a);
    }
}

// ------------------------------------------------------------------
// KD: apply precomputed BN3 scale/bias -> d_out (fp32)
// ------------------------------------------------------------------
__global__ __launch_bounds__(256) void kD_apply(
    const int* __restrict__ fc, const float* __restrict__ ab3,
    float* __restrict__ out)
{
    __shared__ float a3[10], b3[10];
    const int tid = threadIdx.x;
    if (tid < 10) { a3[tid] = ab3[tid]; b3[tid] = ab3[10 + tid]; }
    __syncthreads();
    const int e = blockIdx.x*256 + tid;
    if (e < NB*10) {
        const int m = e % 10;
        out[e] = fmaf(a3[m], (float)fc[e], b3[m]);
    }
}

extern "C" void kernel_launch(void* const* d_in, const int* in_sizes, int n_in,
                              void* d_out, int out_size, void* d_ws, size_t ws_size,
                              hipStream_t stream)
{
    const float* x   = (const float*)d_in[0];
    const float* w1  = (const float*)d_in[1];
    const float* gm1 = (const float*)d_in[2];
    const float* bt1 = (const float*)d_in[3];
    const float* w2  = (const float*)d_in[4];
    const float* gm2 = (const float*)d_in[5];
    const float* bt2 = (const float*)d_in[6];
    const float* w3  = (const float*)d_in[7];
    const float* gm3 = (const float*)d_in[8];
    const float* bt3 = (const float*)d_in[9];
    char* ws = (char*)d_ws;
    int8_t* c1o = (int8_t*)(ws + OFF_C1);
    int8_t* c2o = (int8_t*)(ws + OFF_C2);
    int*    fcb = (int*)(ws + OFF_FC);
    int*    s1  = (int*)(ws + OFF_S1);
    ull*    s2  = (ull*)(ws + OFF_S2);
    ull*    s3  = (ull*)(ws + OFF_S3);
    int*    cnt = (int*)(ws + OFF_CNT);
    int*    T1g = (int*)(ws + OFF_T1);
    int*    T2g = (int*)(ws + OFF_T2);
    float*  ab3 = (float*)(ws + OFF_AB3);
    ull*    w2bp = (ull*)(ws + OFF_W2B);
    ull*    w3bp = (ull*)(ws + OFF_W3B);

    // zeroes S1 + S2 + S3 (incl. counters/thresh scratch in S3 pad)
    (void)hipMemsetAsync(ws + OFF_S1, 0, 12288, stream);
    kA_conv1<<<2053, 256, 0, stream>>>(x, w1, w2, w3, gm1, bt1, c1o, s1,
                                       w2bp, w3bp, T1g, cnt + 0);
    kB_conv2<<<2048, 256, 0, stream>>>(c1o, T1g, w2bp, gm2, bt2, c2o, s2,
                                       T2g, cnt + 1);
    kC_fc   <<<2048, 256, 0, stream>>>(c2o, T2g, w3bp, gm3, bt3, fcb, s3,
                                       ab3, cnt + 2);
    kD_apply<<<320,  256, 0, stream>>>(fcb, ab3, (float*)d_out);
}

// Round 4
// 181.320 us; speedup vs baseline: 2.0868x; 1.8927x over previous
//
#include <hip/hip_runtime.h>
#include <stdint.h>

// Binarized ConvNet via XOR+popcount on packed bits.
// BN stats = exact integer sums (sharded global atomics); BN+sign folded into
// exact per-channel integer thresholds, computed PER BLOCK by wave 0 and
// broadcast via LDS (round-1/2 post-mortem: cross-block "last-block" fence +
// atomic-counter pattern cost ~35ns x 2048 blocks serialized per kernel —
// device-scope __threadfence on 8 non-coherent XCD L2s is expensive; redundant
// in-block math is cheaper).  kB uses LDS-staged coalesced writeout (direct
// register->global stores proved catastrophic: WRITE_SIZE +60%).

#define NB 8192
typedef unsigned long long ull;

// ---- ws layout ----
#define OFF_C1  ((size_t)0)                    // int8 [NB][196pos][32ch]
#define SZ_C1   ((size_t)NB*6272)
#define OFF_C2  (OFF_C1 + SZ_C1)               // int8 [NB][64ch][64pos] (o/2)
#define SZ_C2   ((size_t)NB*4096)
#define OFF_FC  (OFF_C2 + SZ_C2)               // int32 [NB][10]
#define SZ_FC   ((size_t)NB*10*4)
#define OFF_S1  (OFF_FC + SZ_FC)               // int  [8][32][2]   2048 B
#define OFF_S2  (OFF_S1 + 2048)                // ull  [8][64][2]   8192 B
#define OFF_S3  (OFF_S2 + 8192)                // ull  [8][10][2]   (pad 2048)
#define OFF_W2B (OFF_S3 + 2048)                // ull w2bT[8][64] (word-idx major)
#define OFF_W3B (OFF_W2B + 4096)               // ull w3b[10][64ch], bit=pos

// exact integer threshold: bit = (v >= T) ^ flip  <=>  s*v + t > 0
__device__ inline void mk_thresh(double s, double t, int &T, int &flip) {
    if (s > 0.0) {
        int v = (int)floor(-t / s) - 2;
        for (int c = 0; c < 6; ++c) { if (s * (double)v + t > 0.0) break; ++v; }
        T = v; flip = 0;
    } else if (s < 0.0) {
        int v = (int)floor(-t / s) - 2;
        for (int c = 0; c < 6; ++c) { if (!(s * (double)v + t > 0.0)) break; ++v; }
        T = v; flip = 1;
    } else { T = -200; flip = (t > 0.0) ? 0 : 1; }
}
__device__ inline int clampT(int T, int lim) {
    return (T < -lim) ? -lim : (T > lim) ? lim : T;
}

// ------------------------------------------------------------------
// KA: conv1 (binary) + integer BN1 stats.  1 wave = 1 image, 4/block.
// Blocks >= 2048: weight packer, one THREAD per packed word (parallel).
// ------------------------------------------------------------------
__global__ __launch_bounds__(256) void kA_conv1(
    const float* __restrict__ x, const float* __restrict__ w1,
    const float* __restrict__ w2, const float* __restrict__ w3,
    int8_t* __restrict__ c1out, int* __restrict__ stats1,
    ull* __restrict__ w2bT, ull* __restrict__ w3b)
{
    const int tid = threadIdx.x, lane = tid & 63, wv = tid >> 6;

    if (blockIdx.x >= 2048) {   // ---- parallel weight packer blocks ----
        const int t = (blockIdx.x - 2048)*256 + tid;
        if (t < 512) {
            const int idx = t >> 6, k = t & 63;
            const int u = idx >> 1, pr = idx & 1;
            uint32_t lo = 0u, hi = 0u;
            #pragma unroll 8
            for (int c = 0; c < 32; ++c) {
                const float* wp = w2 + (((k*32 + c)*4 + u)*4 + 2*pr);
                lo |= (wp[0] > 0.f ? 1u : 0u) << c;
                hi |= (wp[1] > 0.f ? 1u : 0u) << c;
            }
            w2bT[t] = (ull)lo | ((ull)hi << 32);
        } else if (t < 1152) {
            const int w = t - 512;                 // w = m*64 + ch
            const float* wp = w3 + (size_t)(w >> 6)*4096 + (size_t)(w & 63)*64;
            ull bits = 0ull;
            #pragma unroll 16
            for (int k = 0; k < 64; ++k)
                bits |= (ull)(wp[k] > 0.f ? 1 : 0) << k;
            w3b[w] = bits;
        }
        return;
    }

    __shared__ ull sxb[4][16];              // 784 input sign bits, per wave
    __shared__ uint32_t wfilt[32];          // 25-bit filters
    __shared__ uint32_t outb[4][1568];      // int8 [196][32] as dwords, per wave
    __shared__ int lsum[32], lsq[32];

    if (tid < 32) {
        uint32_t f = 0u;
        #pragma unroll
        for (int q = 0; q < 25; ++q) f |= (w1[tid*25 + q] > 0.f ? 1u : 0u) << q;
        wfilt[tid] = f;
        lsum[tid] = 0; lsq[tid] = 0;
    }
    __syncthreads();          // barrier 1: wfilt + zeroed lsum visible
    const int n = blockIdx.x*4 + wv;
    // phase A: pack 784 input sign bits (13 ballot rounds) — wave-local
    #pragma unroll
    for (int t = 0; t < 13; ++t) {
        const int idx = t*64 + lane;
        const float v = (idx < 784) ? x[(size_t)n*784 + idx] : -1.f;
        const ull bal = __ballot(v > 0.f);
        if (lane == t) sxb[wv][t] = bal;
    }
    if (lane == 13) sxb[wv][13] = 0ull;
    // phase B: each lane computes up to 4 positions, 32 channels each
    for (int t = 0; t < 4; ++t) {
        const int p = t*64 + lane;
        if (p < 196) {
            const int i = p / 14, j = p - i*14;
            const uint32_t cmask = (j == 0) ? 0x1Cu : (j == 13) ? 0x0Fu : 0x1Fu;
            uint32_t win = 0u, vm = 0u;
            #pragma unroll
            for (int u = 0; u < 5; ++u) {
                const int r = 2*i + u - 2;
                if (r >= 0 && r < 28) {
                    const int bp = 28*r, w0 = bp >> 6, sh = bp & 63;
                    const ull a = sxb[wv][w0], b = sxb[wv][w0+1];
                    uint32_t row = (uint32_t)((a >> sh) | ((b << 1) << (63 - sh)));
                    row = (row & 0x0FFFFFFFu) << 2;
                    win |= ((row >> (2*j)) & 31u) << (5*u);
                    vm  |= cmask << (5*u);
                }
            }
            const int nv = __popc(vm);
            uint32_t dw[8];
            #pragma unroll
            for (int d = 0; d < 8; ++d) dw[d] = 0u;
            #pragma unroll
            for (int c = 0; c < 32; ++c) {
                const int diff = __popc((win ^ wfilt[c]) & vm);
                const int o = nv - 2*diff;
                dw[c >> 2] |= (uint32_t)(o & 255) << (8*(c & 3));
            }
            #pragma unroll
            for (int d = 0; d < 8; ++d) outb[wv][p*8 + d] = dw[d];
        }
    }
    {   // coalesced write [n][pos][ch] — wave-local, from LDS staging
        int4* dst = (int4*)(c1out + (size_t)n*6272);
        const int4* src = (const int4*)&outb[wv][0];
        #pragma unroll
        for (int t = 0; t < 7; ++t) {
            const int idx = t*64 + lane;
            if (idx < 392) dst[idx] = src[idx];
        }
    }
    {   // stats: dword reads, lane owns channel-dword d = lane&7
        int s4[4] = {0,0,0,0}, q4[4] = {0,0,0,0};
        const uint32_t* ob32 = &outb[wv][0];
        #pragma unroll
        for (int t = 0; t < 25; ++t) {
            const int idx = t*64 + lane;
            if (idx < 1568) {
                const uint32_t dwv = ob32[idx];
                #pragma unroll
                for (int qq = 0; qq < 4; ++qq) {
                    const int v = (int)((int8_t)(dwv >> (8*qq)));
                    s4[qq] += v; q4[qq] += v*v;
                }
            }
        }
        #pragma unroll
        for (int off = 8; off <= 32; off <<= 1) {
            #pragma unroll
            for (int qq = 0; qq < 4; ++qq) {
                s4[qq] += __shfl_xor(s4[qq], off);
                q4[qq] += __shfl_xor(q4[qq], off);
            }
        }
        if (lane < 8) {
            #pragma unroll
            for (int qq = 0; qq < 4; ++qq) {
                atomicAdd(&lsum[lane*4 + qq], s4[qq]);
                atomicAdd(&lsq[lane*4 + qq], q4[qq]);
            }
        }
    }
    __syncthreads();          // barrier 2: all waves' stats in lsum/lsq
    if (tid < 32) {
        const int shard = blockIdx.x & 7;
        atomicAdd(&stats1[(shard*32 + tid)*2 + 0], lsum[tid]);
        atomicAdd(&stats1[(shard*32 + tid)*2 + 1], lsq[tid]);
    }
}

// ------------------------------------------------------------------
// KB: per-BLOCK BN1 thresholds (wave 0 computes, LDS broadcast under the
// existing barrier), binarize c1, conv2 xor+popc with b128 register
// sliding window (each row read once, broadcast), coalesced LDS-staged
// writeout, int8 o/2 out [n][ch][pos].  1 wave = 1 image.
// ------------------------------------------------------------------
__global__ __launch_bounds__(256) void kB_conv2(
    const int8_t* __restrict__ c1out, const int* __restrict__ stats1,
    const float* __restrict__ gm1, const float* __restrict__ bt1,
    const ull* __restrict__ w2bT,
    int8_t* __restrict__ c2out, ull* __restrict__ stats2)
{
    __shared__ uint32_t BwU[4][14][16]; // packed input bits, 14 used/row, pad 16
    __shared__ int sT1[32];             // per-block thresholds
    __shared__ uint32_t sFlip1;
    __shared__ uint32_t cw[4][64][17];  // staged out dwords, pad 17 -> no conflict
    __shared__ int ssum[64], ssq[64];
    const int tid = threadIdx.x, lane = tid & 63, wv = tid >> 6;
    const int n = blockIdx.x*4 + wv;

    // W fragments from global (coalesced, L2-hot), split lo/hi dwords
    uint32_t Wlo[8], Whi[8];
    #pragma unroll
    for (int idx = 0; idx < 8; ++idx) {
        const uint2 w = ((const uint2*)w2bT)[idx*64 + lane];
        Wlo[idx] = w.x; Whi[idx] = w.y;
    }

    if (tid < 64) { ssum[tid] = 0; ssq[tid] = 0; }
    // per-BLOCK BN1 threshold computation (wave 0 only, 4x less than per-wave)
    int fl = 0;
    if (tid < 32) {
        long long s = 0, q = 0;
        for (int sh = 0; sh < 8; ++sh) {
            s += stats1[(sh*32 + tid)*2 + 0];
            q += stats1[(sh*32 + tid)*2 + 1];
        }
        const double N = 8192.0 * 196.0;
        const double mean = (double)s / N;
        const double var  = (double)q / N - mean*mean;
        const double a = (double)gm1[tid] / sqrt(var + 1e-5);
        const double b = (double)bt1[tid] - mean*a;
        int T; mk_thresh(a, b, T, fl);
        sT1[tid] = clampT(T, 26);
    }
    if (wv == 0) {
        const uint32_t fn1 = ~(uint32_t)__ballot(fl != 0);
        if (lane == 0) sFlip1 = fn1;
    }
    __syncthreads();          // barrier 1: sT1 + sFlip1 + ssum zeros visible
    const uint32_t flipn1 = sFlip1;

    // pack phase — wave-local: binarize own image's 196 positions
    for (int t = lane; t < 196; t += 64) {
        const int r = t / 14, c = t - r*14;
        const uint4* src = (const uint4*)(c1out + ((size_t)n*196 + t)*32);
        const uint4 lo4 = src[0], hi4 = src[1];
        const uint32_t wsrc[8] = {lo4.x, lo4.y, lo4.z, lo4.w, hi4.x, hi4.y, hi4.z, hi4.w};
        uint32_t neg = 0u;
        #pragma unroll
        for (int d = 0; d < 8; ++d) {
            #pragma unroll
            for (int qq = 0; qq < 4; ++qq) {
                const int ch = d*4 + qq;
                const int v = (int)((int8_t)(wsrc[d] >> (8*qq)));
                neg |= ((uint32_t)(v - sT1[ch]) >> 31) << ch;   // 1 iff v<T
            }
        }
        BwU[wv][r][c] = neg ^ flipn1;
    }

    // compute phase: lane = out-channel; b128 register sliding window.
    // pair k = rows (2k, 2k+1); output row i uses pair i-1 (u=0,1) and pair i
    // (u=2,3).  Rows read ONCE via 4x ds_read_b128 each (wave-uniform bcast).
    uint32_t PA[32], PB[32];
#define LOADP(BUF, K)                                                          \
    {                                                                          \
        const uint4* r0 = (const uint4*)&BwU[wv][2*(K)][0];                    \
        const uint4* r1 = (const uint4*)&BwU[wv][2*(K)+1][0];                  \
        _Pragma("unroll")                                                      \
        for (int tt = 0; tt < 4; ++tt) {                                       \
            const uint4 v0 = r0[tt];                                           \
            BUF[4*tt+0] = v0.x; BUF[4*tt+1] = v0.y;                            \
            BUF[4*tt+2] = v0.z; BUF[4*tt+3] = v0.w;                            \
            const uint4 v1 = r1[tt];                                           \
            BUF[16+4*tt+0] = v1.x; BUF[16+4*tt+1] = v1.y;                      \
            BUF[16+4*tt+2] = v1.z; BUF[16+4*tt+3] = v1.w;                      \
        }                                                                      \
    }
#define UT(BUF, RO, UU)                                                        \
    {                                                                          \
        if (j >= 1) { D += __popc(BUF[(RO)*16 + 2*j-2] ^ Wlo[2*(UU)])          \
                         + __popc(BUF[(RO)*16 + 2*j-1] ^ Whi[2*(UU)]);   ++nw; } \
        if (j <= 6) { D += __popc(BUF[(RO)*16 + 2*j]   ^ Wlo[2*(UU)+1])        \
                         + __popc(BUF[(RO)*16 + 2*j+1] ^ Whi[2*(UU)+1]); ++nw; } \
    }
    int s = 0, q = 0;
    LOADP(PA, 0)
    #pragma unroll
    for (int i = 0; i < 8; ++i) {
        if (i >= 1 && i <= 6) {      // prefetch pair i into alternating buffer
            if (i & 1) { LOADP(PB, i) } else { LOADP(PA, i) }
        }
        uint32_t o0 = 0u, o1 = 0u;
        #pragma unroll
        for (int j = 0; j < 8; ++j) {
            int D = 0, nw = 0;
            if (i >= 1) {            // pair i-1: rows 2i-2 (u=0), 2i-1 (u=1)
                if ((i-1) & 1) { UT(PB, 0, 0) UT(PB, 1, 1) }
                else           { UT(PA, 0, 0) UT(PA, 1, 1) }
            }
            if (i <= 6) {            // pair i:   rows 2i (u=2), 2i+1 (u=3)
                if (i & 1) { UT(PB, 0, 2) UT(PB, 1, 3) }
                else       { UT(PA, 0, 2) UT(PA, 1, 3) }
            }
            const int o = 32*nw - D;         // = full/2, exact
            s += o; q += o*o;
            if (j < 4) o0 |= (uint32_t)(o & 255) << (8*j);
            else       o1 |= (uint32_t)(o & 255) << (8*(j-4));
        }
        cw[wv][lane][2*i]     = o0;
        cw[wv][lane][2*i + 1] = o1;
    }
#undef LOADP
#undef UT
    atomicAdd(&ssum[lane], s);
    atomicAdd(&ssq[lane], q);
    {   // coalesced writeout [n][ch][pos] — wave-local, dword-wise
        uint32_t* dst = (uint32_t*)(c2out + (size_t)n*4096);
        #pragma unroll
        for (int t = 0; t < 16; ++t) {
            const int g = t*64 + lane;
            dst[g] = cw[wv][g >> 4][g & 15];
        }
    }
    __syncthreads();          // barrier 2: all waves' stats in ssum/ssq
    if (tid < 64) {
        const int shard = blockIdx.x & 7;
        atomicAdd(&stats2[(shard*64 + tid)*2 + 0], (ull)(long long)ssum[tid]);
        atomicAdd(&stats2[(shard*64 + tid)*2 + 1], (ull)(long long)ssq[tid]);
    }
}

// ------------------------------------------------------------------
// KC: per-BLOCK BN2 thresholds (wave 0 computes lane=ch, LDS broadcast),
// binarize arithmetically, fc xor+popc, packed shuffle reduction, BN3
// stats.  1 wave = 1 image.
// ------------------------------------------------------------------
__global__ __launch_bounds__(256) void kC_fc(
    const int8_t* __restrict__ c2o, const float* __restrict__ gm2,
    const float* __restrict__ bt2, const ull* __restrict__ stats2,
    const ull* __restrict__ w3b,
    int* __restrict__ fc, ull* __restrict__ stats3)
{
    __shared__ int fco[4][10];
    __shared__ int s3[10], q3[10];
    __shared__ int sT2[64];
    __shared__ ull sFlip2;
    const int tid = threadIdx.x, lane = tid & 63, wv = tid >> 6;
    if (tid < 10) { s3[tid] = 0; q3[tid] = 0; }
    // per-BLOCK BN2 thresholds: wave 0, lane = channel (4x less than per-wave)
    if (wv == 0) {
        long long ss = 0, qq = 0;
        for (int sh = 0; sh < 8; ++sh) {
            ss += (long long)stats2[(sh*64 + lane)*2 + 0];
            qq += (long long)stats2[(sh*64 + lane)*2 + 1];
        }
        const double N = 8192.0 * 64.0;
        const double mh = (double)ss / N;
        const double vh = (double)qq / N - mh*mh;
        const double a = (double)gm2[lane] / sqrt(4.0*vh + 1e-5);
        const double b = (double)bt2[lane] - 2.0*mh*a;
        int T, fl; mk_thresh(2.0*a, b, T, fl);
        sT2[lane] = clampT(T, 200);
        const ull fn2 = ~__ballot(fl != 0);
        if (lane == 0) sFlip2 = fn2;
    }
    __syncthreads();          // sT2 + sFlip2 + s3/q3 zeros visible
    const int T2 = sT2[lane];
    const ull flipn2 = sFlip2;
    const int n = blockIdx.x*4 + wv;
    // load own channel's 64 bytes, build bit-word arithmetically
    const uint4* src = (const uint4*)(c2o + (size_t)n*4096 + lane*64);
    uint32_t neglo = 0u, neghi = 0u;
    #pragma unroll
    for (int r4 = 0; r4 < 4; ++r4) {
        const uint4 v4 = src[r4];
        const uint32_t wsrc[4] = {v4.x, v4.y, v4.z, v4.w};
        #pragma unroll
        for (int cc = 0; cc < 4; ++cc) {
            #pragma unroll
            for (int b = 0; b < 4; ++b) {
                const int p = r4*16 + cc*4 + b;
                const int v = (int)((int8_t)(wsrc[cc] >> (8*b)));
                const uint32_t bit = (uint32_t)(v - T2) >> 31;   // 1 iff v<T
                if (p < 32) neglo |= bit << p; else neghi |= bit << (p - 32);
            }
        }
    }
    const ull myw = ((ull)neglo | ((ull)neghi << 32)) ^ flipn2;
    // 10 outputs: popc of mismatch vs w3 words (global, L2-hot), packed reduce
    uint32_t pk[5];
    #pragma unroll
    for (int t = 0; t < 5; ++t) {
        const uint32_t pa = (uint32_t)__popcll(myw ^ w3b[(2*t+0)*64 + lane]);
        const uint32_t pb = (uint32_t)__popcll(myw ^ w3b[(2*t+1)*64 + lane]);
        pk[t] = pa | (pb << 16);
    }
    #pragma unroll
    for (int off = 32; off >= 1; off >>= 1) {
        #pragma unroll
        for (int t = 0; t < 5; ++t) pk[t] += __shfl_xor(pk[t], off);
    }
    if (lane == 0) {
        #pragma unroll
        for (int m = 0; m < 10; ++m) {
            const int tot = (pk[m >> 1] >> (16*(m & 1))) & 0xFFFF;
            fco[wv][m] = 4096 - 2*tot;
        }
    }
    __syncthreads();
    if (tid < 40) {
        const int li = tid / 10, m = tid - li*10;
        const int o = fco[li][m];
        fc[(size_t)(blockIdx.x*4 + li)*10 + m] = o;
        atomicAdd(&s3[m], o);
        atomicAdd(&q3[m], o*o);
    }
    __syncthreads();
    if (tid < 10) {
        const int shard = blockIdx.x & 7;
        atomicAdd(&stats3[(shard*10 + tid)*2 + 0], (ull)(long long)s3[tid]);
        atomicAdd(&stats3[(shard*10 + tid)*2 + 1], (ull)(long long)q3[tid]);
    }
}

// ------------------------------------------------------------------
// KD: reduce BN3 stats (per block, redundant) + apply -> d_out (fp32)
// ------------------------------------------------------------------
__global__ __launch_bounds__(256) void kD_apply(
    const int* __restrict__ fc, const float* __restrict__ gm3,
    const float* __restrict__ bt3, const ull* __restrict__ stats3,
    float* __restrict__ out)
{
    __shared__ float a3[10], b3[10];
    const int tid = threadIdx.x;
    if (tid < 10) {
        long long s = 0, q = 0;
        for (int sh = 0; sh < 8; ++sh) {
            s += (long long)stats3[(sh*10 + tid)*2 + 0];
            q += (long long)stats3[(sh*10 + tid)*2 + 1];
        }
        const double N = 8192.0;
        const double mean = (double)s / N;
        const double var  = (double)q / N - mean*mean;
        const double a = (double)gm3[tid] / sqrt(var + 1e-5);
        a3[tid] = (float)a;
        b3[tid] = (float)((double)bt3[tid] - mean*a);
    }
    __syncthreads();
    const int e = blockIdx.x*256 + tid;
    if (e < NB*10) {
        const int m = e % 10;
        out[e] = fmaf(a3[m], (float)fc[e], b3[m]);
    }
}

extern "C" void kernel_launch(void* const* d_in, const int* in_sizes, int n_in,
                              void* d_out, int out_size, void* d_ws, size_t ws_size,
                              hipStream_t stream)
{
    const float* x   = (const float*)d_in[0];
    const float* w1  = (const float*)d_in[1];
    const float* gm1 = (const float*)d_in[2];
    const float* bt1 = (const float*)d_in[3];
    const float* w2  = (const float*)d_in[4];
    const float* gm2 = (const float*)d_in[5];
    const float* bt2 = (const float*)d_in[6];
    const float* w3  = (const float*)d_in[7];
    const float* gm3 = (const float*)d_in[8];
    const float* bt3 = (const float*)d_in[9];
    char* ws = (char*)d_ws;
    int8_t* c1o = (int8_t*)(ws + OFF_C1);
    int8_t* c2o = (int8_t*)(ws + OFF_C2);
    int*    fcb = (int*)(ws + OFF_FC);
    int*    s1  = (int*)(ws + OFF_S1);
    ull*    s2  = (ull*)(ws + OFF_S2);
    ull*    s3  = (ull*)(ws + OFF_S3);
    ull*    w2bp = (ull*)(ws + OFF_W2B);
    ull*    w3bp = (ull*)(ws + OFF_W3B);

    (void)hipMemsetAsync(ws + OFF_S1, 0, 12288, stream);
    kA_conv1<<<2053, 256, 0, stream>>>(x, w1, w2, w3, c1o, s1, w2bp, w3bp);
    kB_conv2<<<2048, 256, 0, stream>>>(c1o, s1, gm1, bt1, w2bp, c2o, s2);
    kC_fc   <<<2048, 256, 0, stream>>>(c2o, gm2, bt2, s2, w3bp, fcb, s3);
    kD_apply<<<320,  256, 0, stream>>>(fcb, gm3, bt3, s3, (float*)d_out);
}